// Round 1
// baseline (2094.336 us; speedup 1.0000x reference)
//
#include <hip/hip_runtime.h>
#include <math.h>

#define N_NODES 20000
#define E2      240000     // directed edges (2E)
#define EP      120000     // positive edges
#define ENEG    600000     // negative edges
#define ETOT    720000     // EP + ENEG

__device__ __forceinline__ float logsigf(float x) {
    // log_sigmoid(x) = min(x,0) - log1p(exp(-|x|))
    return fminf(x, 0.0f) - log1pf(expf(-fabsf(x)));
}

// ---------------- K1: m1 = x @ W1   [20000,256] @ [256,256] ----------------
__global__ __launch_bounds__(256) void k_mm_xW1(const float* __restrict__ x,
                                                const float* __restrict__ W1,
                                                float* __restrict__ m1) {
    __shared__ float xl[8 * 256];
    const int tid = threadIdx.x;
    const long base = (long)blockIdx.x * 8 * 256;
    const float4* src = (const float4*)(x + base);
    float4* dst = (float4*)xl;
    for (int i = tid; i < 512; i += 256) dst[i] = src[i];
    __syncthreads();
    float acc[8] = {0.f,0.f,0.f,0.f,0.f,0.f,0.f,0.f};
    for (int k = 0; k < 256; k += 4) {
        const float w0 = W1[(k + 0) * 256 + tid];
        const float w1 = W1[(k + 1) * 256 + tid];
        const float w2 = W1[(k + 2) * 256 + tid];
        const float w3 = W1[(k + 3) * 256 + tid];
#pragma unroll
        for (int r = 0; r < 8; ++r) {
            const float4 xv = *(const float4*)&xl[r * 256 + k];
            acc[r] += xv.x * w0 + xv.y * w1 + xv.z * w2 + xv.w * w3;
        }
    }
#pragma unroll
    for (int r = 0; r < 8; ++r) m1[base + r * 256 + tid] = acc[r];
}

// ---------------- K2/K4: scatter-add rows (dim 256), atomics ----------------
__global__ __launch_bounds__(256) void k_scatter256(const float* __restrict__ feat,
                                                    float* __restrict__ out,
                                                    const int* __restrict__ srcs,
                                                    const int* __restrict__ dsts) {
    const int e = blockIdx.x;
    const int t = threadIdx.x;
    const int s = srcs[e], d = dsts[e];
    atomicAdd(&out[(long)d * 256 + t], feat[(long)s * 256 + t]);
}

// ---------------- K3: h1 = relu(LN(h1pre + b1)) in place ----------------
__global__ __launch_bounds__(256) void k_ln_relu(float* __restrict__ h,
                                                 const float* __restrict__ b1,
                                                 const float* __restrict__ g1,
                                                 const float* __restrict__ bt1) {
    const int w = threadIdx.x >> 6;
    const int lane = threadIdx.x & 63;
    const long row = (long)blockIdx.x * 4 + w;
    float4 v = *(const float4*)(h + row * 256 + lane * 4);
    const float4 b = *(const float4*)(b1 + lane * 4);
    v.x += b.x; v.y += b.y; v.z += b.z; v.w += b.w;
    float s  = v.x + v.y + v.z + v.w;
    float sq = v.x * v.x + v.y * v.y + v.z * v.z + v.w * v.w;
    for (int o = 32; o > 0; o >>= 1) {
        s  += __shfl_xor(s, o, 64);
        sq += __shfl_xor(sq, o, 64);
    }
    const float mean = s * (1.0f / 256.0f);
    const float var  = sq * (1.0f / 256.0f) - mean * mean;
    const float rs = rsqrtf(var + 1e-5f);
    const float4 g  = *(const float4*)(g1 + lane * 4);
    const float4 bt = *(const float4*)(bt1 + lane * 4);
    float4 o4;
    o4.x = fmaxf((v.x - mean) * rs * g.x + bt.x, 0.f);
    o4.y = fmaxf((v.y - mean) * rs * g.y + bt.y, 0.f);
    o4.z = fmaxf((v.z - mean) * rs * g.z + bt.z, 0.f);
    o4.w = fmaxf((v.w - mean) * rs * g.w + bt.w, 0.f);
    *(float4*)(h + row * 256 + lane * 4) = o4;
}

// ------- K5: mu/logvar from agg1, z = mu + eps*exp(lv/2), kl partial -------
__global__ __launch_bounds__(256) void k_mulv(const float* __restrict__ agg1,
                                              const float* __restrict__ Wmu,
                                              const float* __restrict__ bmu,
                                              const float* __restrict__ Wlv,
                                              const float* __restrict__ blv,
                                              const float* __restrict__ eps,
                                              float* __restrict__ z,
                                              double* __restrict__ kl_accum) {
    __shared__ float rows[4 * 256];
    const int tid = threadIdx.x;
    const long base = (long)blockIdx.x * 4 * 256;
    ((float4*)rows)[tid] = ((const float4*)(agg1 + base))[tid];
    __syncthreads();
    const int r = tid >> 6;
    const int c = tid & 63;
    float amu = 0.f, alv = 0.f;
    for (int k = 0; k < 256; k += 4) {
        const float4 a = *(const float4*)&rows[r * 256 + k];
        amu += a.x * Wmu[(k+0)*64+c] + a.y * Wmu[(k+1)*64+c]
             + a.z * Wmu[(k+2)*64+c] + a.w * Wmu[(k+3)*64+c];
        alv += a.x * Wlv[(k+0)*64+c] + a.y * Wlv[(k+1)*64+c]
             + a.z * Wlv[(k+2)*64+c] + a.w * Wlv[(k+3)*64+c];
    }
    const float mu = amu + bmu[c];
    const float lv = alv + blv[c];
    const long i = (long)blockIdx.x * 4 + r;
    const float ev = eps[i * 64 + c];
    z[i * 64 + c] = mu + ev * expf(0.5f * lv);
    float term = 1.0f + lv - mu * mu - expf(lv);
    for (int o = 32; o > 0; o >>= 1) term += __shfl_xor(term, o, 64);
    if (c == 0) atomicAdd(kl_accum, (double)term);
}

// ---------------- K6: degree count, then dis = rsqrt(deg+1) ----------------
__global__ void k_deg(const int* __restrict__ pd, float* __restrict__ deg) {
    const int e = blockIdx.x * 256 + threadIdx.x;
    if (e < EP) atomicAdd(&deg[pd[e]], 1.0f);
}
__global__ void k_dis(float* __restrict__ deg_dis) {
    const int i = blockIdx.x * 256 + threadIdx.x;
    if (i < N_NODES) deg_dis[i] = rsqrtf(fmaxf(deg_dis[i] + 1.0f, 1.0f));
}

// -------- K7a/K8a: normalized scatter (dim 64) over positive edges --------
__global__ __launch_bounds__(256) void k_scatter_norm64(const float* __restrict__ feat,
                                                        float* __restrict__ out,
                                                        const int* __restrict__ ps,
                                                        const int* __restrict__ pd,
                                                        const float* __restrict__ dis) {
    const int e = blockIdx.x * 4 + (threadIdx.x >> 6);
    const int t = threadIdx.x & 63;
    const int s = ps[e], d = pd[e];
    const float w = dis[s] * dis[d];
    atomicAdd(&out[(long)d * 64 + t], feat[(long)s * 64 + t] * w);
}

// --- K7b/K8b: out = relu((agg + self*dis^2) @ Wd + bd), 64x64 matmul ---
__global__ __launch_bounds__(256) void k_dec_mm(const float* __restrict__ agg,
                                                const float* __restrict__ self_feat,
                                                const float* __restrict__ dis,
                                                const float* __restrict__ Wd,
                                                const float* __restrict__ bd,
                                                float* __restrict__ out) {
    __shared__ float rows[4 * 64];
    __shared__ float sW[64 * 64];
    const int tid = threadIdx.x;
    {
        const float4* w4 = (const float4*)Wd;
        float4* sw4 = (float4*)sW;
        for (int i = tid; i < 1024; i += 256) sw4[i] = w4[i];
    }
    const int r = tid >> 6, c = tid & 63;
    const long i = (long)blockIdx.x * 4 + r;
    const float dsi = dis[i];
    rows[r * 64 + c] = agg[i * 64 + c] + self_feat[i * 64 + c] * dsi * dsi;
    __syncthreads();
    float acc = 0.f;
    for (int k = 0; k < 64; k += 4) {
        const float4 a = *(const float4*)&rows[r * 64 + k];
        acc += a.x * sW[(k+0)*64+c] + a.y * sW[(k+1)*64+c]
             + a.z * sW[(k+2)*64+c] + a.w * sW[(k+3)*64+c];
    }
    out[i * 64 + c] = fmaxf(acc + bd[c], 0.f);
}

// ---------------- K9: edge MLP + weighted BCE partial sums ----------------
// block = 256 threads = 4 waves; each wave handles 8 edges; Wa staged in
// k-halves (2x 32KB) so static LDS stays under 64KB. Inner loop per k:
// 1x ds_read_b32 (Wa, conflict-free) + 2x ds_read_b128 broadcast (phi) + 8 FMA.
__global__ __launch_bounds__(256) void k_edge_mlp(const float* __restrict__ h2,
                                                  const int* __restrict__ pos,
                                                  const int* __restrict__ neg,
                                                  const float* __restrict__ Wa,
                                                  const float* __restrict__ ba,
                                                  const float* __restrict__ Wb,
                                                  const float* __restrict__ bb,
                                                  const float* __restrict__ tau,
                                                  double* __restrict__ recon_accum) {
    __shared__ float sWa[128 * 64];      // 32 KB (half of Wa)
    __shared__ float sPhi[4][128 * 8];   // 16 KB, [wave][k][edge]
    __shared__ float sBaWb[128];
    const int tid = threadIdx.x;
    const int w = tid >> 6, lane = tid & 63;
    if (tid < 64) { sBaWb[tid] = ba[tid]; sBaWb[64 + tid] = Wb[tid]; }
    const long ebase = (long)blockIdx.x * 32 + (long)w * 8;
    float hu[8], hv[8];
#pragma unroll
    for (int e = 0; e < 8; ++e) {
        const long j = ebase + e;
        int u, v;
        if (j < EP) { u = pos[j]; v = pos[EP + j]; }
        else        { u = neg[j - EP]; v = neg[ENEG + (j - EP)]; }
        hu[e] = h2[(long)u * 64 + lane];
        hv[e] = h2[(long)v * 64 + lane];
    }
    float acc[8] = {0.f,0.f,0.f,0.f,0.f,0.f,0.f,0.f};
    for (int half = 0; half < 2; ++half) {
        __syncthreads();
        {   // stage this half of Wa (rows half*128 .. half*128+127)
            const float4* w4 = (const float4*)(Wa + (long)half * 128 * 64);
            float4* sw4 = (float4*)sWa;
            for (int i = tid; i < 2048; i += 256) sw4[i] = w4[i];
        }
#pragma unroll
        for (int e = 0; e < 8; ++e) {
            const float p0 = half ? fabsf(hu[e] - hv[e]) : hu[e];
            const float p1 = half ? hu[e] * hv[e]        : hv[e];
            sPhi[w][lane * 8 + e] = p0;
            sPhi[w][(64 + lane) * 8 + e] = p1;
        }
        __syncthreads();
        for (int k = 0; k < 128; ++k) {
            const float a = sWa[k * 64 + lane];
            const float4 q0 = *(const float4*)&sPhi[w][k * 8];
            const float4 q1 = *(const float4*)&sPhi[w][k * 8 + 4];
            acc[0] += q0.x * a; acc[1] += q0.y * a;
            acc[2] += q0.z * a; acc[3] += q0.w * a;
            acc[4] += q1.x * a; acc[5] += q1.y * a;
            acc[6] += q1.z * a; acc[7] += q1.w * a;
        }
    }
    const float taum = fmaxf(tau[0], 1e-4f);
    const float bav = sBaWb[lane];
    const float wbv = sBaWb[64 + lane];
    float lsum = 0.f;
#pragma unroll
    for (int e = 0; e < 8; ++e) {
        float val = fmaxf(acc[e] + bav, 0.f) * wbv;
        for (int o = 32; o > 0; o >>= 1) val += __shfl_xor(val, o, 64);
        if (lane == 0) {
            const float logit = (val + bb[0]) / taum;
            const long j = ebase + e;
            lsum += (j < EP) ? 5.0f * logsigf(logit) : logsigf(-logit);
        }
    }
    if (lane == 0) atomicAdd(recon_accum, (double)lsum);
}

// ---------------- K10: finalize ----------------
__global__ void k_final(const double* __restrict__ accum, float* __restrict__ out) {
    if (threadIdx.x == 0) {
        const double recon = -accum[0] / (double)ETOT;
        const double kl = -0.5 * accum[1] / ((double)N_NODES * 64.0);
        out[0] = (float)(recon + kl);
        out[1] = (float)recon;
        out[2] = (float)kl;
    }
}

extern "C" void kernel_launch(void* const* d_in, const int* in_sizes, int n_in,
                              void* d_out, int out_size, void* d_ws, size_t ws_size,
                              hipStream_t stream) {
    const float* x   = (const float*)d_in[0];
    const float* eps = (const float*)d_in[1];
    const int* EI    = (const int*)d_in[2];   // [2, 240000]
    const int* pos   = (const int*)d_in[3];   // [2, 120000]
    const int* neg   = (const int*)d_in[4];   // [2, 600000]
    const float* W1  = (const float*)d_in[5];
    const float* b1  = (const float*)d_in[6];
    const float* g1  = (const float*)d_in[7];
    const float* bt1 = (const float*)d_in[8];
    const float* Wmu = (const float*)d_in[9];
    const float* bmu = (const float*)d_in[10];
    const float* Wlv = (const float*)d_in[11];
    const float* blv = (const float*)d_in[12];
    const float* Wd1 = (const float*)d_in[13];
    const float* bd1 = (const float*)d_in[14];
    const float* Wd2 = (const float*)d_in[15];
    const float* bd2 = (const float*)d_in[16];
    const float* Wa  = (const float*)d_in[17];
    const float* ba  = (const float*)d_in[18];
    const float* Wb  = (const float*)d_in[19];
    const float* bb  = (const float*)d_in[20];
    const float* tau = (const float*)d_in[21];

    const int* e_src = EI;
    const int* e_dst = EI + E2;
    const int* ps = pos;
    const int* pd = pos + EP;

    // workspace layout (floats). Region A is reused: m1 -> agg1 -> h2.
    float* ws = (float*)d_ws;
    float* m1   = ws;                 // [20000,256]  (A)
    float* agg1 = ws;                 //              (A, after m1 dead)
    float* h2   = ws;                 // [20000,64]   (A, after agg1 dead)
    float* h1   = ws + 5120000;       // [20000,256]  (B)
    float* z    = ws + 10240000;      // [20000,64]
    float* dis  = ws + 11520000;      // [20000]
    float* aggz = ws + 11552768;      // [20000,64]
    float* hdec = ws + 12832768;      // [20000,64]
    float* aggh = ws + 14112768;      // [20000,64]
    double* accum = (double*)(ws + 15392768); // [0]=recon_sum [1]=kl_sum

    hipMemsetAsync(accum, 0, 16, stream);

    // encoder layer 1
    k_mm_xW1<<<2500, 256, 0, stream>>>(x, W1, m1);
    hipMemsetAsync(h1, 0, (size_t)5120000 * 4, stream);
    k_scatter256<<<E2, 256, 0, stream>>>(m1, h1, e_src, e_dst);
    k_ln_relu<<<5000, 256, 0, stream>>>(h1, b1, g1, bt1);

    // shared aggregation for mu/logvar, then z + kl
    hipMemsetAsync(agg1, 0, (size_t)5120000 * 4, stream);
    k_scatter256<<<E2, 256, 0, stream>>>(h1, agg1, e_src, e_dst);
    k_mulv<<<5000, 256, 0, stream>>>(agg1, Wmu, bmu, Wlv, blv, eps, z, accum + 1);

    // decoder normalization
    hipMemsetAsync(dis, 0, (size_t)N_NODES * 4, stream);
    k_deg<<<(EP + 255) / 256, 256, 0, stream>>>(pd, dis);
    k_dis<<<(N_NODES + 255) / 256, 256, 0, stream>>>(dis);

    // decoder layer 1
    hipMemsetAsync(aggz, 0, (size_t)1280000 * 4, stream);
    k_scatter_norm64<<<EP / 4, 256, 0, stream>>>(z, aggz, ps, pd, dis);
    k_dec_mm<<<5000, 256, 0, stream>>>(aggz, z, dis, Wd1, bd1, hdec);

    // decoder layer 2
    hipMemsetAsync(aggh, 0, (size_t)1280000 * 4, stream);
    k_scatter_norm64<<<EP / 4, 256, 0, stream>>>(hdec, aggh, ps, pd, dis);
    k_dec_mm<<<5000, 256, 0, stream>>>(aggh, hdec, dis, Wd2, bd2, h2);

    // edge MLP + loss
    k_edge_mlp<<<ETOT / 32, 256, 0, stream>>>(h2, pos, neg, Wa, ba, Wb, bb, tau, accum);
    k_final<<<1, 64, 0, stream>>>(accum, (float*)d_out);
}

// Round 2
// 1271.680 us; speedup vs baseline: 1.6469x; 1.6469x over previous
//
#include <hip/hip_runtime.h>
#include <math.h>

#define N_NODES 20000
#define E2      240000     // directed edges (2E)
#define EP      120000     // positive edges
#define ENEG    600000     // negative edges
#define ETOT    720000     // EP + ENEG
#define PAD     264        // bf16 row stride for MFMA LDS tiles (+8 pad)

typedef __attribute__((ext_vector_type(8))) short bf16x8;
typedef __attribute__((ext_vector_type(4))) float f32x4;

__device__ __forceinline__ float logsigf(float x) {
    // log_sigmoid(x) = min(x,0) - log1p(exp(-|x|))
    return fminf(x, 0.0f) - log1pf(expf(-fabsf(x)));
}

__device__ __forceinline__ unsigned short f2bf(float f) {
    unsigned u = __float_as_uint(f);
    u += 0x7FFF + ((u >> 16) & 1);   // RNE
    return (unsigned short)(u >> 16);
}

// ---------------- K1: m1 = x @ W1   [20000,256] @ [256,256] ----------------
__global__ __launch_bounds__(256) void k_mm_xW1(const float* __restrict__ x,
                                                const float* __restrict__ W1,
                                                float* __restrict__ m1) {
    __shared__ float xl[8 * 256];
    const int tid = threadIdx.x;
    const long base = (long)blockIdx.x * 8 * 256;
    const float4* src = (const float4*)(x + base);
    float4* dst = (float4*)xl;
    for (int i = tid; i < 512; i += 256) dst[i] = src[i];
    __syncthreads();
    float acc[8] = {0.f,0.f,0.f,0.f,0.f,0.f,0.f,0.f};
    for (int k = 0; k < 256; k += 4) {
        const float w0 = W1[(k + 0) * 256 + tid];
        const float w1 = W1[(k + 1) * 256 + tid];
        const float w2 = W1[(k + 2) * 256 + tid];
        const float w3 = W1[(k + 3) * 256 + tid];
#pragma unroll
        for (int r = 0; r < 8; ++r) {
            const float4 xv = *(const float4*)&xl[r * 256 + k];
            acc[r] += xv.x * w0 + xv.y * w1 + xv.z * w2 + xv.w * w3;
        }
    }
#pragma unroll
    for (int r = 0; r < 8; ++r) m1[base + r * 256 + tid] = acc[r];
}

// ---------------- K2/K4: scatter-add rows (dim 256), atomics ----------------
__global__ __launch_bounds__(256) void k_scatter256(const float* __restrict__ feat,
                                                    float* __restrict__ out,
                                                    const int* __restrict__ srcs,
                                                    const int* __restrict__ dsts) {
    const int e = blockIdx.x;
    const int t = threadIdx.x;
    const int s = srcs[e], d = dsts[e];
    atomicAdd(&out[(long)d * 256 + t], feat[(long)s * 256 + t]);
}

// ---------------- K3: h1 = relu(LN(h1pre + b1)) in place ----------------
__global__ __launch_bounds__(256) void k_ln_relu(float* __restrict__ h,
                                                 const float* __restrict__ b1,
                                                 const float* __restrict__ g1,
                                                 const float* __restrict__ bt1) {
    const int w = threadIdx.x >> 6;
    const int lane = threadIdx.x & 63;
    const long row = (long)blockIdx.x * 4 + w;
    float4 v = *(const float4*)(h + row * 256 + lane * 4);
    const float4 b = *(const float4*)(b1 + lane * 4);
    v.x += b.x; v.y += b.y; v.z += b.z; v.w += b.w;
    float s  = v.x + v.y + v.z + v.w;
    float sq = v.x * v.x + v.y * v.y + v.z * v.z + v.w * v.w;
    for (int o = 32; o > 0; o >>= 1) {
        s  += __shfl_xor(s, o, 64);
        sq += __shfl_xor(sq, o, 64);
    }
    const float mean = s * (1.0f / 256.0f);
    const float var  = sq * (1.0f / 256.0f) - mean * mean;
    const float rs = rsqrtf(var + 1e-5f);
    const float4 g  = *(const float4*)(g1 + lane * 4);
    const float4 bt = *(const float4*)(bt1 + lane * 4);
    float4 o4;
    o4.x = fmaxf((v.x - mean) * rs * g.x + bt.x, 0.f);
    o4.y = fmaxf((v.y - mean) * rs * g.y + bt.y, 0.f);
    o4.z = fmaxf((v.z - mean) * rs * g.z + bt.z, 0.f);
    o4.w = fmaxf((v.w - mean) * rs * g.w + bt.w, 0.f);
    *(float4*)(h + row * 256 + lane * 4) = o4;
}

// ------- K5: mu/logvar from agg1, z = mu + eps*exp(lv/2), kl partial -------
__global__ __launch_bounds__(256) void k_mulv(const float* __restrict__ agg1,
                                              const float* __restrict__ Wmu,
                                              const float* __restrict__ bmu,
                                              const float* __restrict__ Wlv,
                                              const float* __restrict__ blv,
                                              const float* __restrict__ eps,
                                              float* __restrict__ z,
                                              double* __restrict__ kl_accum) {
    __shared__ float rows[4 * 256];
    const int tid = threadIdx.x;
    const long base = (long)blockIdx.x * 4 * 256;
    ((float4*)rows)[tid] = ((const float4*)(agg1 + base))[tid];
    __syncthreads();
    const int r = tid >> 6;
    const int c = tid & 63;
    float amu = 0.f, alv = 0.f;
    for (int k = 0; k < 256; k += 4) {
        const float4 a = *(const float4*)&rows[r * 256 + k];
        amu += a.x * Wmu[(k+0)*64+c] + a.y * Wmu[(k+1)*64+c]
             + a.z * Wmu[(k+2)*64+c] + a.w * Wmu[(k+3)*64+c];
        alv += a.x * Wlv[(k+0)*64+c] + a.y * Wlv[(k+1)*64+c]
             + a.z * Wlv[(k+2)*64+c] + a.w * Wlv[(k+3)*64+c];
    }
    const float mu = amu + bmu[c];
    const float lv = alv + blv[c];
    const long i = (long)blockIdx.x * 4 + r;
    const float ev = eps[i * 64 + c];
    z[i * 64 + c] = mu + ev * expf(0.5f * lv);
    float term = 1.0f + lv - mu * mu - expf(lv);
    for (int o = 32; o > 0; o >>= 1) term += __shfl_xor(term, o, 64);
    if (c == 0) atomicAdd(kl_accum, (double)term);
}

// ---------------- K6: degree count, then dis = rsqrt(deg+1) ----------------
__global__ void k_deg(const int* __restrict__ pd, float* __restrict__ deg) {
    const int e = blockIdx.x * 256 + threadIdx.x;
    if (e < EP) atomicAdd(&deg[pd[e]], 1.0f);
}
__global__ void k_dis(float* __restrict__ deg_dis) {
    const int i = blockIdx.x * 256 + threadIdx.x;
    if (i < N_NODES) deg_dis[i] = rsqrtf(fmaxf(deg_dis[i] + 1.0f, 1.0f));
}

// -------- K7a/K8a: normalized scatter (dim 64) over positive edges --------
__global__ __launch_bounds__(256) void k_scatter_norm64(const float* __restrict__ feat,
                                                        float* __restrict__ out,
                                                        const int* __restrict__ ps,
                                                        const int* __restrict__ pd,
                                                        const float* __restrict__ dis) {
    const int e = blockIdx.x * 4 + (threadIdx.x >> 6);
    const int t = threadIdx.x & 63;
    const int s = ps[e], d = pd[e];
    const float w = dis[s] * dis[d];
    atomicAdd(&out[(long)d * 64 + t], feat[(long)s * 64 + t] * w);
}

// --- K7b/K8b: out = relu((agg + self*dis^2) @ Wd + bd), 64x64 matmul ---
__global__ __launch_bounds__(256) void k_dec_mm(const float* __restrict__ agg,
                                                const float* __restrict__ self_feat,
                                                const float* __restrict__ dis,
                                                const float* __restrict__ Wd,
                                                const float* __restrict__ bd,
                                                float* __restrict__ out) {
    __shared__ float rows[4 * 64];
    __shared__ float sW[64 * 64];
    const int tid = threadIdx.x;
    {
        const float4* w4 = (const float4*)Wd;
        float4* sw4 = (float4*)sW;
        for (int i = tid; i < 1024; i += 256) sw4[i] = w4[i];
    }
    const int r = tid >> 6, c = tid & 63;
    const long i = (long)blockIdx.x * 4 + r;
    const float dsi = dis[i];
    rows[r * 64 + c] = agg[i * 64 + c] + self_feat[i * 64 + c] * dsi * dsi;
    __syncthreads();
    float acc = 0.f;
    for (int k = 0; k < 64; k += 4) {
        const float4 a = *(const float4*)&rows[r * 64 + k];
        acc += a.x * sW[(k+0)*64+c] + a.y * sW[(k+1)*64+c]
             + a.z * sW[(k+2)*64+c] + a.w * sW[(k+3)*64+c];
    }
    out[i * 64 + c] = fmaxf(acc + bd[c], 0.f);
}

// ----- K9-prep: WaT[n][k'] = bf16(Wa[k][n]), k' = d*4+part, k = part*64+d -----
// The k-permutation lets each lane write its 4 phi parts (hu,hv,|hu-hv|,hu*hv)
// for one dim d as ONE contiguous ds_write_b64 in the MFMA kernel.
__global__ void k_prep_wa(const float* __restrict__ Wa, unsigned short* __restrict__ WaT) {
    const int idx = blockIdx.x * 256 + threadIdx.x;   // 0..16383
    const int n = idx >> 8, kp = idx & 255;
    const int d = kp >> 2, part = kp & 3;
    WaT[idx] = f2bf(Wa[(part * 64 + d) * 64 + n]);
}

// ---------------- K9: edge MLP via MFMA + weighted BCE ----------------
// 4 waves/block; wave = 2 M-tiles x 16 edges = 32 edges; block = 128 edges.
// phi [16,256] bf16 in LDS (PAD=264 rows: 2-way bank alias = free),
// WaT [64,256] bf16 in LDS. 16x16x32 bf16 MFMA, fp32 accumulate.
__global__ __launch_bounds__(256) void k_edge_mlp_mfma(const float* __restrict__ h2,
                                                       const int* __restrict__ pos,
                                                       const int* __restrict__ neg,
                                                       const unsigned short* __restrict__ WaT,
                                                       const float* __restrict__ ba,
                                                       const float* __restrict__ Wb,
                                                       const float* __restrict__ bb,
                                                       const float* __restrict__ tau,
                                                       double* __restrict__ recon_accum) {
    __shared__ unsigned short sWb[64 * PAD];       // 33792 B
    __shared__ unsigned short sPhi[4][16 * PAD];   // 33792 B
    __shared__ double sRed[4];
    const int tid = threadIdx.x;
    const int w = tid >> 6, lane = tid & 63;
    const int l15 = lane & 15, quad = lane >> 4;

    // stage WaT -> LDS (16B chunks, coalesced read, 16B-aligned LDS writes)
    for (int i = tid; i < 2048; i += 256) {
        const int n = i >> 5, k8 = (i & 31) << 3;
        *(int4*)&sWb[n * PAD + k8] = *(const int4*)&WaT[n * 256 + k8];
    }
    __syncthreads();

    // per-lane epilogue constants (n = t*16 + l15)
    float ban[4], wbn[4];
#pragma unroll
    for (int t = 0; t < 4; ++t) {
        ban[t] = ba[t * 16 + l15];
        wbn[t] = Wb[t * 16 + l15];
    }
    const float bb0 = bb[0];
    const float taum = fmaxf(tau[0], 1e-4f);

    const long ebase = (long)blockIdx.x * 128 + (long)w * 32;
    float lsum = 0.f;

    for (int mt = 0; mt < 2; ++mt) {
        // build phi tile: 16 edges, lane covers dim d=lane; one b64 write/edge
#pragma unroll
        for (int m = 0; m < 16; ++m) {
            const long j = ebase + mt * 16 + m;
            int u, v;
            if (j < EP) { u = pos[j]; v = pos[EP + j]; }
            else        { u = neg[j - EP]; v = neg[ENEG + (j - EP)]; }
            const float hu = h2[(long)u * 64 + lane];
            const float hv = h2[(long)v * 64 + lane];
            union { unsigned short s[4]; unsigned long long ll; } pk;
            pk.s[0] = f2bf(hu);
            pk.s[1] = f2bf(hv);
            pk.s[2] = f2bf(fabsf(hu - hv));
            pk.s[3] = f2bf(hu * hv);
            *(unsigned long long*)&sPhi[w][m * PAD + lane * 4] = pk.ll;
        }
        // MFMA: D[16 edges][64 hid] = phi[16][256] @ Wa[256][64]
        f32x4 acc[4];
#pragma unroll
        for (int t = 0; t < 4; ++t) acc[t] = (f32x4){0.f, 0.f, 0.f, 0.f};
        for (int ks = 0; ks < 8; ++ks) {
            const bf16x8 af = *(const bf16x8*)&sPhi[w][l15 * PAD + ks * 32 + quad * 8];
#pragma unroll
            for (int t = 0; t < 4; ++t) {
                const bf16x8 bf = *(const bf16x8*)&sWb[(t * 16 + l15) * PAD + ks * 32 + quad * 8];
                acc[t] = __builtin_amdgcn_mfma_f32_16x16x32_bf16(af, bf, acc[t], 0, 0, 0);
            }
        }
        // epilogue: relu(+ba)*Wb, reduce over n (16 lanes x 4 tiles), logits
#pragma unroll
        for (int r = 0; r < 4; ++r) {
            float s = 0.f;
#pragma unroll
            for (int t = 0; t < 4; ++t) s += fmaxf(acc[t][r] + ban[t], 0.f) * wbn[t];
            for (int o = 8; o > 0; o >>= 1) s += __shfl_xor(s, o, 64);
            if (l15 == 0) {
                const long j = ebase + mt * 16 + quad * 4 + r;  // D row = quad*4+r
                const float logit = (s + bb0) / taum;
                lsum += (j < EP) ? 5.0f * logsigf(logit) : logsigf(-logit);
            }
        }
    }
    // wave reduce (contributors are lanes 0,16,32,48), then block reduce
    lsum += __shfl_xor(lsum, 16, 64);
    lsum += __shfl_xor(lsum, 32, 64);
    if (lane == 0) sRed[w] = (double)lsum;
    __syncthreads();
    if (tid == 0) atomicAdd(recon_accum, sRed[0] + sRed[1] + sRed[2] + sRed[3]);
}

// ---------------- K10: finalize ----------------
__global__ void k_final(const double* __restrict__ accum, float* __restrict__ out) {
    if (threadIdx.x == 0) {
        const double recon = -accum[0] / (double)ETOT;
        const double kl = -0.5 * accum[1] / ((double)N_NODES * 64.0);
        out[0] = (float)(recon + kl);
        out[1] = (float)recon;
        out[2] = (float)kl;
    }
}

extern "C" void kernel_launch(void* const* d_in, const int* in_sizes, int n_in,
                              void* d_out, int out_size, void* d_ws, size_t ws_size,
                              hipStream_t stream) {
    const float* x   = (const float*)d_in[0];
    const float* eps = (const float*)d_in[1];
    const int* EI    = (const int*)d_in[2];   // [2, 240000]
    const int* pos   = (const int*)d_in[3];   // [2, 120000]
    const int* neg   = (const int*)d_in[4];   // [2, 600000]
    const float* W1  = (const float*)d_in[5];
    const float* b1  = (const float*)d_in[6];
    const float* g1  = (const float*)d_in[7];
    const float* bt1 = (const float*)d_in[8];
    const float* Wmu = (const float*)d_in[9];
    const float* bmu = (const float*)d_in[10];
    const float* Wlv = (const float*)d_in[11];
    const float* blv = (const float*)d_in[12];
    const float* Wd1 = (const float*)d_in[13];
    const float* bd1 = (const float*)d_in[14];
    const float* Wd2 = (const float*)d_in[15];
    const float* bd2 = (const float*)d_in[16];
    const float* Wa  = (const float*)d_in[17];
    const float* ba  = (const float*)d_in[18];
    const float* Wb  = (const float*)d_in[19];
    const float* bb  = (const float*)d_in[20];
    const float* tau = (const float*)d_in[21];

    const int* e_src = EI;
    const int* e_dst = EI + E2;
    const int* ps = pos;
    const int* pd = pos + EP;

    // workspace layout (floats). Region A is reused: m1 -> agg1 -> h2.
    float* ws = (float*)d_ws;
    float* m1   = ws;                 // [20000,256]  (A)
    float* agg1 = ws;                 //              (A, after m1 dead)
    float* h2   = ws;                 // [20000,64]   (A, after agg1 dead)
    float* h1   = ws + 5120000;       // [20000,256]  (B)
    float* z    = ws + 10240000;      // [20000,64]
    float* dis  = ws + 11520000;      // [20000]
    float* aggz = ws + 11552768;      // [20000,64]
    float* hdec = ws + 12832768;      // [20000,64]
    float* aggh = ws + 14112768;      // [20000,64]
    double* accum = (double*)(ws + 15392768); // [0]=recon_sum [1]=kl_sum
    unsigned short* WaT = (unsigned short*)(ws + 15392776); // [64,256] bf16

    hipMemsetAsync(accum, 0, 16, stream);
    k_prep_wa<<<64, 256, 0, stream>>>(Wa, WaT);

    // encoder layer 1
    k_mm_xW1<<<2500, 256, 0, stream>>>(x, W1, m1);
    hipMemsetAsync(h1, 0, (size_t)5120000 * 4, stream);
    k_scatter256<<<E2, 256, 0, stream>>>(m1, h1, e_src, e_dst);
    k_ln_relu<<<5000, 256, 0, stream>>>(h1, b1, g1, bt1);

    // shared aggregation for mu/logvar, then z + kl
    hipMemsetAsync(agg1, 0, (size_t)5120000 * 4, stream);
    k_scatter256<<<E2, 256, 0, stream>>>(h1, agg1, e_src, e_dst);
    k_mulv<<<5000, 256, 0, stream>>>(agg1, Wmu, bmu, Wlv, blv, eps, z, accum + 1);

    // decoder normalization
    hipMemsetAsync(dis, 0, (size_t)N_NODES * 4, stream);
    k_deg<<<(EP + 255) / 256, 256, 0, stream>>>(pd, dis);
    k_dis<<<(N_NODES + 255) / 256, 256, 0, stream>>>(dis);

    // decoder layer 1
    hipMemsetAsync(aggz, 0, (size_t)1280000 * 4, stream);
    k_scatter_norm64<<<EP / 4, 256, 0, stream>>>(z, aggz, ps, pd, dis);
    k_dec_mm<<<5000, 256, 0, stream>>>(aggz, z, dis, Wd1, bd1, hdec);

    // decoder layer 2
    hipMemsetAsync(aggh, 0, (size_t)1280000 * 4, stream);
    k_scatter_norm64<<<EP / 4, 256, 0, stream>>>(hdec, aggh, ps, pd, dis);
    k_dec_mm<<<5000, 256, 0, stream>>>(aggh, hdec, dis, Wd2, bd2, h2);

    // edge MLP + loss (MFMA)
    k_edge_mlp_mfma<<<ETOT / 128, 256, 0, stream>>>(h2, pos, neg, WaT, ba, Wb, bb, tau, accum);
    k_final<<<1, 64, 0, stream>>>(accum, (float*)d_out);
}